// Round 4
// baseline (1384.492 us; speedup 1.0000x reference)
//
#include <hip/hip_runtime.h>

#define NT    256
#define LANES 8   // 8 half-wave FFT lanes of 32 threads; each lane owns a row-pair

__device__ __forceinline__ float2 cmul(float2 a, float2 b) {
    return make_float2(a.x * b.x - a.y * b.y, a.x * b.y + a.y * b.x);
}

// 5-bit bit-reversal (involution)
constexpr int br5(int i) {
    return ((i & 1) << 4) | ((i & 2) << 2) | (i & 4) | ((i & 8) >> 2) | ((i & 16) >> 4);
}

// W32^j = e^{-2*pi*i*j/32} = TWC[j] + i*TWS[j]
__device__ constexpr float TWC[16] = {
    1.0f,                0.980785280403230f,  0.923879532511287f,  0.831469612302545f,
    0.707106781186548f,  0.555570233019602f,  0.382683432365090f,  0.195090322016128f,
    0.0f,               -0.195090322016128f, -0.382683432365090f, -0.555570233019602f,
   -0.707106781186548f, -0.831469612302545f, -0.923879532511287f, -0.980785280403230f};
__device__ constexpr float TWS[16] = {
   -0.0f,               -0.195090322016128f, -0.382683432365090f, -0.555570233019602f,
   -0.707106781186548f, -0.831469612302545f, -0.923879532511287f, -0.980785280403230f,
   -1.0f,               -0.980785280403230f, -0.923879532511287f, -0.831469612302545f,
   -0.707106781186548f, -0.555570233019602f, -0.382683432365090f, -0.195090322016128f};

// In-register 32-pt radix-2 DIF FFT. Output: v[r] = X[br5(r)].
__device__ __forceinline__ void fft32(float2 (&v)[32]) {
#pragma unroll
    for (int s = 16; s >= 1; s >>= 1) {
#pragma unroll
        for (int base = 0; base < 32; base += 2 * s) {
#pragma unroll
            for (int j = 0; j < s; ++j) {
                float2 u = v[base + j];
                float2 w = v[base + j + s];
                float2 d = make_float2(u.x - w.x, u.y - w.y);
                v[base + j] = make_float2(u.x + w.x, u.y + w.y);
                const int ti = j * (16 / s);
                if (ti == 0)
                    v[base + j + s] = d;
                else if (ti == 8)  // W = -i
                    v[base + j + s] = make_float2(d.y, -d.x);
                else
                    v[base + j + s] = make_float2(d.x * TWC[ti] - d.y * TWS[ti],
                                                  d.x * TWS[ti] + d.y * TWC[ti]);
            }
        }
    }
}

// 1024-pt FFT for a 32-thread lane, data in x[32] (thread tau owns elements
// n1=tau + 32*n2 at entry). Four-step: fft32 -> twiddle W_1024^{tau*k2} ->
// LDS transpose (XOR layout, conflict-free, wave-synchronous) -> fft32.
// Result: x[r] = X[32*br5(r) + tau].
__device__ __forceinline__ void fft1024_lane(float2 (&x)[32], char* ldsL,
                                             const float2 (&lo)[8], const float2 (&hi)[4],
                                             int wb, int rb) {
    fft32(x);
    // inter-stage twiddle: x[r] *= W_1024^{tau * br5(r)}  (tables lo/hi per thread)
#pragma unroll
    for (int rr = 0; rr < 32; ++rr) {
        const int k2 = br5(rr);
        if (k2 == 0) continue;
        float2 tw;
        if (k2 < 8)             tw = lo[k2];
        else if ((k2 & 7) == 0) tw = hi[k2 >> 3];
        else                    tw = cmul(hi[k2 >> 3], lo[k2 & 7]);
        x[rr] = cmul(x[rr], tw);
    }
    // transpose: write G'[tau][k2] at elem 32*tau + (k2^tau); read row n1, col tau
#pragma unroll
    for (int rr = 0; rr < 32; ++rr) {
        *(float2*)(ldsL + (wb ^ (br5(rr) << 3))) = x[rr];
    }
    __builtin_amdgcn_wave_barrier();
#pragma unroll
    for (int n1 = 0; n1 < 32; ++n1) {
        x[n1] = *(const float2*)(ldsL + (rb ^ (264 * n1)));
    }
    fft32(x);
}

__global__ __launch_bounds__(NT, 2) void hole_fft_kernel(
    const float* __restrict__ h, const float* __restrict__ r, const float* __restrict__ t,
    float* __restrict__ out)
{
    __shared__ float2 lds[LANES * 1024];  // 8 KiB per lane, 64 KiB total

    const int tid = threadIdx.x;
    const int L   = tid >> 5;
    const int tau = tid & 31;
    const int pairIdx = blockIdx.x * LANES + L;
    const int row0 = pairIdx * 2, row1 = row0 + 1;

    char* ldsL = (char*)(lds + (L << 10));
    const int wb = 264 * tau;      // byte write base within lane region
    const int rb = tau << 3;       // byte read base
    const int pl = (tid & 32) | ((32 - tau) & 31);  // shfl partner (wave-lane)
    const bool t0 = (tau == 0);

    // per-thread twiddle tables for W_1024^{tau*k2}: lo[b]=w^b, hi[a]=w^{8a}
    float2 lo[8], hi[4];
    {
        float rev = -(float)tau * (1.0f / 1024.0f);   // revolutions, pre-reduced
        float2 w = make_float2(__builtin_amdgcn_cosf(rev), __builtin_amdgcn_sinf(rev));
        lo[0] = make_float2(1.0f, 0.0f);
        lo[1] = w;
#pragma unroll
        for (int k = 2; k < 8; ++k) lo[k] = cmul(lo[k - 1], w);
        hi[0] = make_float2(1.0f, 0.0f);
        hi[1] = cmul(lo[7], w);
        hi[2] = cmul(hi[1], hi[1]);
        hi[3] = cmul(hi[2], hi[1]);
    }

    float2 Zf[32];   // Z spectrum, this thread's f = 32*br5(r) + tau
    float2 x[32];
    float acc0 = 0.0f, acc1 = 0.0f;

    // it=0: Z = FFT(r0 + i r1)   -> stash in Zf
    // it=1: X0 = FFT(h0 + i t0)  -> acc0
    // it=2: X1 = FFT(h1 + i t1)  -> acc1
#pragma unroll 1
    for (int it = 0; it < 3; ++it) {
        const float* pa;
        const float* pb;
        if (it == 0)      { pa = r + (size_t)row0 * 1024 + tau; pb = r + (size_t)row1 * 1024 + tau; }
        else if (it == 1) { pa = h + (size_t)row0 * 1024 + tau; pb = t + (size_t)row0 * 1024 + tau; }
        else              { pa = h + (size_t)row1 * 1024 + tau; pb = t + (size_t)row1 * 1024 + tau; }

#pragma unroll
        for (int n2 = 0; n2 < 32; ++n2) {
            x[n2] = make_float2(pa[n2 * 32], pb[n2 * 32]);  // imm-offset loads
        }

        fft1024_lane(x, ldsL, lo, hi, wb, rb);

        if (it == 0) {
#pragma unroll
            for (int rr = 0; rr < 32; ++rr) Zf[rr] = x[rr];
        } else {
            const bool first = (it == 1);
            float accl = 0.0f;
            // score contribution per f: with A=X_f, B=X_{-f}, Z_f=a+ib, Z_{-f}=c+id:
            //  conj(H)T = Im(A*B)/2 - i(|A|^2-|B|^2)/4
            //  term0 = Im*(a+c)/4 - dm*(b-d)/8 ; term1 = Im*(b+d)/4 + dm*(a-c)/8
            // accl accumulates 4*term; final scale 1/(4*1024).
#pragma unroll
            for (int rr = 0; rr < 32; ++rr) {
                const int rp = 31 - rr;                       // partner's register
                const int rs = br5((32 - br5(rr)) & 31);      // own register when tau==0
                float xgx = __shfl(x[rp].x, pl, 64);
                float xgy = __shfl(x[rp].y, pl, 64);
                float zgx = __shfl(Zf[rp].x, pl, 64);
                float zgy = __shfl(Zf[rp].y, pl, 64);
                xgx = t0 ? x[rs].x : xgx;
                xgy = t0 ? x[rs].y : xgy;
                zgx = t0 ? Zf[rs].x : zgx;
                zgy = t0 ? Zf[rs].y : zgy;
                float im = x[rr].x * xgy + x[rr].y * xgx;     // Im(A*B)
                float mX = x[rr].x * x[rr].x + x[rr].y * x[rr].y;
                float mG = xgx * xgx + xgy * xgy;
                float dm = mX - mG;
                float sA1 = Zf[rr].x + zgx, sB1 = 0.5f * (zgy - Zf[rr].y);
                float sA2 = Zf[rr].y + zgy, sB2 = 0.5f * (Zf[rr].x - zgx);
                float sA = first ? sA1 : sA2;
                float sB = first ? sB1 : sB2;
                accl += im * sA + dm * sB;
            }
            if (first) acc0 = accl; else acc1 = accl;
        }
    }

    // reduce across the 32-thread lane
#pragma unroll
    for (int off = 16; off > 0; off >>= 1) {
        acc0 += __shfl_xor(acc0, off, 64);
        acc1 += __shfl_xor(acc1, off, 64);
    }
    if (t0) {
        out[row0] = acc0 * (1.0f / 4096.0f);
        out[row1] = acc1 * (1.0f / 4096.0f);
    }
}

extern "C" void kernel_launch(void* const* d_in, const int* in_sizes, int n_in,
                              void* d_out, int out_size, void* d_ws, size_t ws_size,
                              hipStream_t stream) {
    const float* h = (const float*)d_in[0];
    const float* r = (const float*)d_in[1];
    const float* t = (const float*)d_in[2];
    float* out = (float*)d_out;
    int nblocks = out_size / (LANES * 2);   // 131072/16 = 8192
    hipLaunchKernelGGL(hole_fft_kernel, dim3(nblocks), dim3(NT), 0, stream,
                       h, r, t, out);
}

// Round 5
// 472.046 us; speedup vs baseline: 2.9330x; 2.9330x over previous
//
#include <hip/hip_runtime.h>

#define NT 256

// 4-bit bit-reversal (involution)
constexpr int br4(int i) {
    return ((i & 1) << 3) | ((i & 2) << 1) | ((i & 4) >> 1) | ((i & 8) >> 3);
}

// W_32^j = e^{-2*pi*i*j/32} = W32C[j] + i*W32S[j], j=0..15  (W_16^t = index 2t)
__device__ constexpr float W32C[16] = {
    1.0f,                0.980785280403230f,  0.923879532511287f,  0.831469612302545f,
    0.707106781186548f,  0.555570233019602f,  0.382683432365090f,  0.195090322016128f,
    0.0f,               -0.195090322016128f, -0.382683432365090f, -0.555570233019602f,
   -0.707106781186548f, -0.831469612302545f, -0.923879532511287f, -0.980785280403230f};
__device__ constexpr float W32S[16] = {
   -0.0f,               -0.195090322016128f, -0.382683432365090f, -0.555570233019602f,
   -0.707106781186548f, -0.831469612302545f, -0.923879532511287f, -0.980785280403230f,
   -1.0f,               -0.980785280403230f, -0.923879532511287f, -0.831469612302545f,
   -0.707106781186548f, -0.555570233019602f, -0.382683432365090f, -0.195090322016128f};

__device__ __forceinline__ float2 cmul(float2 a, float2 b) {
    return make_float2(a.x * b.x - a.y * b.y, a.x * b.y + a.y * b.x);
}
__device__ __forceinline__ float2 csqr(float2 a) {
    return make_float2(a.x * a.x - a.y * a.y, 2.0f * a.x * a.y);
}

// In-register 16-pt radix-2 DIF FFT. Output: v[r] = X[br4(r)].
__device__ __forceinline__ void fft16(float2 (&v)[16]) {
#pragma unroll
    for (int s = 8; s >= 1; s >>= 1) {
#pragma unroll
        for (int base = 0; base < 16; base += 2 * s) {
#pragma unroll
            for (int j = 0; j < s; ++j) {
                float2 u = v[base + j];
                float2 w = v[base + j + s];
                float2 d = make_float2(u.x - w.x, u.y - w.y);
                v[base + j] = make_float2(u.x + w.x, u.y + w.y);
                const int ti = j * (8 / s);   // W_16^ti = W_32^(2*ti)
                if (ti == 0)
                    v[base + j + s] = d;
                else if (ti == 4)             // W_16^4 = -i
                    v[base + j + s] = make_float2(d.y, -d.x);
                else
                    v[base + j + s] = make_float2(d.x * W32C[2 * ti] - d.y * W32S[2 * ti],
                                                  d.x * W32S[2 * ti] + d.y * W32C[2 * ti]);
            }
        }
    }
}

// Distributed 32-pt FFT across a lane-pair (lane, lane^32).
// Entry: reg r holds y[r + 16*b5]. Exit: reg r holds Y[2*br4(r) + b5].
__device__ __forceinline__ void fft32d(float2 (&x)[16], bool hi) {
#pragma unroll
    for (int r = 0; r < 16; ++r) {
        float ox = __shfl_xor(x[r].x, 32, 64);
        float oy = __shfl_xor(x[r].y, 32, 64);
        float sx = x[r].x + ox, sy = x[r].y + oy;
        float dx = ox - x[r].x, dy = oy - x[r].y;
        float tx, ty;
        if (r == 0)      { tx = dx; ty = dy; }
        else if (r == 8) { tx = dy; ty = -dx; }     // * W_32^8 = -i
        else             { tx = dx * W32C[r] - dy * W32S[r];
                           ty = dx * W32S[r] + dy * W32C[r]; }
        x[r].x = hi ? tx : sx;
        x[r].y = hi ? ty : sy;
    }
    fft16(x);
}

__global__ __launch_bounds__(NT) void hole_fft_kernel(
    const float* __restrict__ gh, const float* __restrict__ gr, const float* __restrict__ gt,
    float* __restrict__ out)
{
    __shared__ float2 lds[4 * 1024];   // 8 KiB per wave, 32 KiB total

    const int tid  = threadIdx.x;
    const int wv   = tid >> 6;
    const int lane = tid & 63;
    const int b5   = lane >> 5;
    const int tau  = lane & 31;
    const bool hi  = (b5 != 0);
    const bool t00 = (lane == 0);

    const int pairIdx = blockIdx.x * 4 + wv;
    const int row0 = pairIdx * 2, row1 = row0 + 1;

    char* ldsW = (char*)lds + (wv << 13);

    // transpose addressing (XOR-column layout, elem = 32*row + (row^col)):
    //   write (row=tau, col-key k2=2*br4(r)+b5): byte = (264*tau) ^ (b5<<3) ^ (br4(r)<<4)
    //   read  (row=n1=rp+16*b5, col-key tau):    byte = (4224*b5) ^ (tau<<3) ^ (264*rp)
    const int wbyte = (264 * tau) ^ (b5 << 3);
    const int rbyte = (4224 * b5) ^ (tau << 3);
    const int gofs  = tau + (b5 << 9);   // element offset of this thread's load base

    // shfl partner lane for f <-> -f: (1-b5, 32-tau); tau==0 -> self
    const int pl = (tau == 0) ? lane : (((lane & 32) ^ 32) | (32 - tau));

    // twiddle table for W_1024^{tau*k2}, k2 = 2m+b5: Tlo[m]=w^{2m+b5} (m<8), Thi=w^16
    float2 Tlo[8], Thi;
    {
        float rev = -(float)tau * (1.0f / 1024.0f);   // revolutions, pre-reduced
        float2 w  = make_float2(__builtin_amdgcn_cosf(rev), __builtin_amdgcn_sinf(rev));
        float2 w2 = csqr(w);
        Tlo[0] = hi ? w : make_float2(1.0f, 0.0f);
#pragma unroll
        for (int j = 1; j < 8; ++j) Tlo[j] = cmul(Tlo[j - 1], w2);
        Thi = csqr(csqr(csqr(w2)));                   // w^16
    }

    float2 x[16], Zf[16];
    float acc0 = 0.0f, acc1 = 0.0f;

    // it=0: Z = FFT(r0 + i r1); it=1: X0 = FFT(h0 + i t0) -> acc0; it=2: X1 -> acc1
#pragma unroll 1
    for (int it = 0; it < 3; ++it) {
        const float* pa;
        const float* pb;
        if (it == 0)      { pa = gr + (size_t)row0 * 1024; pb = gr + (size_t)row1 * 1024; }
        else if (it == 1) { pa = gh + (size_t)row0 * 1024; pb = gt + (size_t)row0 * 1024; }
        else              { pa = gh + (size_t)row1 * 1024; pb = gt + (size_t)row1 * 1024; }
        pa += gofs; pb += gofs;

        // element n = gofs + 32*rp  (coalesced: two 128B segments per instr)
#pragma unroll
        for (int rp = 0; rp < 16; ++rp)
            x[rp] = make_float2(pa[rp * 32], pb[rp * 32]);

        // step 1: FFT32 over n2 (distributed). reg r -> k2 = 2*br4(r)+b5
        fft32d(x, hi);

        // step 2: twiddle W_1024^{tau*k2}
#pragma unroll
        for (int rr = 0; rr < 16; ++rr) {
            const int m = br4(rr);
            float2 tw = (m < 8) ? Tlo[m] : cmul(Tlo[m - 8], Thi);
            x[rr] = cmul(x[rr], tw);
        }

        // step 3: LDS transpose (conflict-free XOR layout, wave-synchronous)
        __builtin_amdgcn_wave_barrier();
#pragma unroll
        for (int rr = 0; rr < 16; ++rr)
            *(float2*)(ldsW + (wbyte ^ (br4(rr) << 4))) = x[rr];
        __builtin_amdgcn_wave_barrier();
#pragma unroll
        for (int rp = 0; rp < 16; ++rp)
            x[rp] = *(const float2*)(ldsW + (rbyte ^ (264 * rp)));

        // step 4: FFT32 over n1 (distributed). reg r -> f = 32*(2*br4(r)+b5) + tau
        fft32d(x, hi);

        if (it == 0) {
#pragma unroll
            for (int rr = 0; rr < 16; ++rr) Zf[rr] = x[rr];
        } else {
            const bool first = (it == 1);
            float accl = 0.0f;
#pragma unroll
            for (int rr = 0; rr < 16; ++rr) {
                const int rp = 15 - rr;                      // partner's register
                const int rs = br4((16 - br4(rr)) & 15);     // lane-0 self register
                float fx = __shfl(x[rp].x, pl, 64);
                float fy = __shfl(x[rp].y, pl, 64);
                float gx = __shfl(Zf[rp].x, pl, 64);
                float gy = __shfl(Zf[rp].y, pl, 64);
                fx = t00 ? x[rs].x  : fx;
                fy = t00 ? x[rs].y  : fy;
                gx = t00 ? Zf[rs].x : gx;
                gy = t00 ? Zf[rs].y : gy;
                float im = x[rr].x * fy + x[rr].y * fx;                    // Im(A*B)
                float dm = (x[rr].x * x[rr].x + x[rr].y * x[rr].y)
                         - (fx * fx + fy * fy);                            // |A|^2-|B|^2
                float sA = first ? (Zf[rr].x + gx) : (Zf[rr].y + gy);
                float sB = first ? (0.5f * (gy - Zf[rr].y)) : (0.5f * (Zf[rr].x - gx));
                accl += im * sA + dm * sB;
            }
            if (first) acc0 = accl; else acc1 = accl;
        }
    }

    // reduce across the 64-lane wave
#pragma unroll
    for (int off = 32; off > 0; off >>= 1) {
        acc0 += __shfl_xor(acc0, off, 64);
        acc1 += __shfl_xor(acc1, off, 64);
    }
    if (t00) {
        out[row0] = acc0 * (1.0f / 4096.0f);
        out[row1] = acc1 * (1.0f / 4096.0f);
    }
}

extern "C" void kernel_launch(void* const* d_in, const int* in_sizes, int n_in,
                              void* d_out, int out_size, void* d_ws, size_t ws_size,
                              hipStream_t stream) {
    const float* h = (const float*)d_in[0];
    const float* r = (const float*)d_in[1];
    const float* t = (const float*)d_in[2];
    float* out = (float*)d_out;
    int nblocks = out_size / 8;   // 4 row-pairs per block -> 16384
    hipLaunchKernelGGL(hole_fft_kernel, dim3(nblocks), dim3(NT), 0, stream,
                       h, r, t, out);
}